// Round 9
// baseline (295.540 us; speedup 1.0000x reference)
//
#include <hip/hip_runtime.h>

// SGConv: K=3 hops of \hat{A} x (symmetric gcn_norm w/ self-loops), then Linear.
// N=100000, E=1600000, F_in=32, F_out=64.
// Round 9: fp16 halving was near-neutral -> hop gathers are LINE-granular
// (128B fill per random row; 6.4MB state > 4MB L2/XCD misses to L3).
// Fix: propagation is feature-independent -> split state into two 16-feature
// halves (3.2MB each < 4MB L2/XCD) and run each hop as 2 sequential passes.
// Random read-set is L2-resident per pass; col/gout use nontemporal hints so
// streaming traffic doesn't evict state lines. Also: k_bin scan -> shfl scan.

#define F_IN 32
#define F_OUT 64
#define BKT_SHIFT 9                  // 512 nodes per dst-bucket
#define BKT (1 << BKT_SHIFT)
#define EPB 4096                     // edges per binning/histogram block
#define MAXB 256                     // >= number of buckets (196 for N=100000)

typedef float f4 __attribute__((ext_vector_type(4)));
typedef _Float16 h4 __attribute__((ext_vector_type(4)));  // 8B: 4 halves

// Per-block LDS histogram of dst-buckets -> MAXB global atomics per block.
__global__ __launch_bounds__(256) void k_bucket_hist(const int* __restrict__ dst,
                                                     int* __restrict__ bcount, int E) {
    __shared__ int h[MAXB];
    int tid = threadIdx.x;
    h[tid] = 0;
    __syncthreads();
    int base = blockIdx.x * EPB;
    for (int k = 0; k < EPB / 256; ++k) {
        int i = base + k * 256 + tid;
        if (i < E) atomicAdd(&h[dst[i] >> BKT_SHIFT], 1);
    }
    __syncthreads();
    if (h[tid]) atomicAdd(&bcount[tid], h[tid]);
}

// One block (MAXB threads): exclusive scan of bucket counts.
__global__ __launch_bounds__(MAXB) void k_scan_buckets(const int* __restrict__ bcount,
                                                       int* __restrict__ colbase,
                                                       int* __restrict__ gcursor) {
    __shared__ int sc[MAXB];
    int tid = threadIdx.x;
    int c = bcount[tid];
    sc[tid] = c;
    __syncthreads();
    for (int off = 1; off < MAXB; off <<= 1) {
        int t = (tid >= off) ? sc[tid - off] : 0;
        __syncthreads();
        sc[tid] += t;
        __syncthreads();
    }
    int excl = sc[tid] - c;
    colbase[tid] = excl;
    gcursor[tid] = excl;
    if (tid == MAXB - 1) colbase[MAXB] = sc[tid];
}

// Bin edges into dst-buckets; records packed to 4B: (src << 9) | (dst & 511).
// Scan over the 256 LDS counters done via shfl two-level (saves ~30 barriers).
__global__ __launch_bounds__(256) void k_bin(const int* __restrict__ ei,
                                             int* __restrict__ gcursor,
                                             unsigned* __restrict__ binned, int E) {
    __shared__ unsigned stage[EPB];          // 16 KB
    __shared__ unsigned char bid[EPB];       // 4 KB
    __shared__ int hist[MAXB], lscan[MAXB], lbase[MAXB], fcur[MAXB];
    __shared__ int wsum[4];
    int tid = threadIdx.x;
    int base = blockIdx.x * EPB;
    int cnt = E - base; if (cnt > EPB) cnt = EPB;

    hist[tid] = 0;
    __syncthreads();
    for (int k = 0; k < EPB / 256; ++k) {
        int i = base + k * 256 + tid;
        if (i < E) atomicAdd(&hist[ei[E + i] >> BKT_SHIFT], 1);
    }
    __syncthreads();
    {
        int c = hist[tid];
        int lane = tid & 63, wid = tid >> 6;
        int inc = c;
#pragma unroll
        for (int off = 1; off < 64; off <<= 1) {
            int t = __shfl_up(inc, off);
            if (lane >= off) inc += t;
        }
        if (lane == 63) wsum[wid] = inc;
        __syncthreads();
        if (wid == 0) {
            int v = (lane < 4) ? wsum[lane] : 0;
#pragma unroll
            for (int off = 1; off < 4; off <<= 1) {
                int t = __shfl_up(v, off);
                if (lane >= off) v += t;
            }
            if (lane < 4) wsum[lane] = v;
        }
        __syncthreads();
        int excl = inc + (wid ? wsum[wid - 1] : 0) - c;
        lscan[tid] = excl;
        fcur[tid] = excl;
        lbase[tid] = c ? atomicAdd(&gcursor[tid], c) : 0;
    }
    __syncthreads();
    for (int k = 0; k < EPB / 256; ++k) {
        int i = base + k * 256 + tid;
        if (i < E) {
            unsigned s = (unsigned)ei[i];
            unsigned d = (unsigned)ei[E + i];
            int b = d >> BKT_SHIFT;
            int loc = atomicAdd(&fcur[b], 1);
            stage[loc] = (s << BKT_SHIFT) | (d & (BKT - 1));
            bid[loc] = (unsigned char)b;
        }
    }
    __syncthreads();
    for (int k = 0; k < EPB / 256; ++k) {
        int idx = k * 256 + tid;
        if (idx < cnt) {
            int b = bid[idx];
            binned[lbase[b] + (idx - lscan[b])] = stage[idx];
        }
    }
}

// One workgroup (512 thr) per 512-node bucket: LDS hist -> shfl scan ->
// dinv/rp (coalesced) -> col scatter via LDS cursors. No global atomics.
__global__ __launch_bounds__(512) void k_fill3(const unsigned* __restrict__ binned,
                                               const int* __restrict__ colbase,
                                               float* __restrict__ dinv,
                                               int* __restrict__ rp,
                                               int* __restrict__ col, int N) {
    __shared__ int h[BKT];
    __shared__ int wsum[8];
    int tid = threadIdx.x;
    int b = blockIdx.x;
    int base_node = b << BKT_SHIFT;
    int cbase = colbase[b];
    int cend  = colbase[b + 1];

    h[tid] = 0;
    __syncthreads();
    for (int e = cbase + tid; e < cend; e += 512)
        atomicAdd(&h[binned[e] & (BKT - 1)], 1);
    __syncthreads();

    int deg = h[tid];
    int lane = tid & 63, wid = tid >> 6;
    int inc = deg;
#pragma unroll
    for (int off = 1; off < 64; off <<= 1) {
        int t = __shfl_up(inc, off);
        if (lane >= off) inc += t;
    }
    if (lane == 63) wsum[wid] = inc;
    __syncthreads();
    if (wid == 0) {
        int v = (lane < 8) ? wsum[lane] : 0;
#pragma unroll
        for (int off = 1; off < 8; off <<= 1) {
            int t = __shfl_up(v, off);
            if (lane >= off) v += t;
        }
        if (lane < 8) wsum[lane] = v;
    }
    __syncthreads();
    int incl = inc + (wid ? wsum[wid - 1] : 0);
    int excl = incl - deg;

    int node = base_node + tid;
    if (node < N) {
        dinv[node] = rsqrtf(1.0f + (float)deg);
        rp[node + 1] = cbase + incl;
    }
    h[tid] = excl;
    if (b == 0 && tid == 0) rp[0] = 0;
    __syncthreads();

    for (int e = cbase + tid; e < cend; e += 512) {
        unsigned r = binned[e];
        int slot = cbase + atomicAdd(&h[r & (BKT - 1)], 1);
        col[slot] = (int)(r >> BKT_SHIFT);
    }
}

// Prescale + split: half0[n][0..15] = fp16(dinv*x[n][0..15]), half1 = features 16..31.
__global__ void k_prescale(const f4* __restrict__ x, const float* __restrict__ dinv,
                           h4* __restrict__ g0, h4* __restrict__ g1, int N8) {
    int t = blockIdx.x * blockDim.x + threadIdx.x;
    if (t < N8) {
        int n = t >> 3, c = t & 7;
        f4 v = dinv[n] * x[t];
        h4 hv = __builtin_convertvector(v, h4);
        h4* dst = (c < 4) ? g0 : g1;
        dst[n * 4 + (c & 3)] = hv;
    }
}

// One hop pass on a 16-feature half (3.2MB, L2-resident per XCD):
// out[n] = sc * (sum g[src] + g[n]); sc = dinv^2 (mid) / dinv (final).
// 4 lanes/row (8B each -> 32B row). col loads + gout stores nontemporal
// so streaming traffic doesn't evict the state lines.
__global__ __launch_bounds__(256) void k_hop_pass(const int* __restrict__ rp,
                                                  const int* __restrict__ col,
                                                  const float* __restrict__ dinv,
                                                  const h4* __restrict__ gin,
                                                  h4* __restrict__ gout,
                                                  int N, int final_hop) {
    int t = blockIdx.x * blockDim.x + threadIdx.x;
    int n = t >> 2;
    if (n >= N) return;
    int q = t & 3;
    int e0 = rp[n], e1 = rp[n + 1];
    f4 a0 = __builtin_convertvector(gin[n * 4 + q], f4);  // self-loop term
    f4 a1 = {0.f, 0.f, 0.f, 0.f};
    int e = e0;
    for (; e + 3 < e1; e += 4) {
        int s0 = __builtin_nontemporal_load(col + e);
        int s1 = __builtin_nontemporal_load(col + e + 1);
        int s2 = __builtin_nontemporal_load(col + e + 2);
        int s3 = __builtin_nontemporal_load(col + e + 3);
        h4 h0 = gin[s0 * 4 + q];
        h4 h1 = gin[s1 * 4 + q];
        h4 h2 = gin[s2 * 4 + q];
        h4 h3 = gin[s3 * 4 + q];
        a0 += __builtin_convertvector(h0, f4);
        a1 += __builtin_convertvector(h1, f4);
        a0 += __builtin_convertvector(h2, f4);
        a1 += __builtin_convertvector(h3, f4);
    }
    for (; e < e1; ++e)
        a0 += __builtin_convertvector(gin[__builtin_nontemporal_load(col + e) * 4 + q], f4);
    float di = dinv[n];
    float sc = final_hop ? di : di * di;
    f4 r = sc * (a0 + a1);
    __builtin_nontemporal_store(__builtin_convertvector(r, h4), &gout[n * 4 + q]);
}

// out[n][o] = b[o] + sum_f h[n][f] * W[o][f]; h split into two fp16 halves.
__global__ __launch_bounds__(256) void k_linear(const _Float16* __restrict__ h0,
                                                const _Float16* __restrict__ h1,
                                                const float* __restrict__ W,
                                                const float* __restrict__ b,
                                                float* __restrict__ out, int N) {
    __shared__ float Wl[F_OUT][F_IN + 1];
    __shared__ float hl[4][F_IN];
    int tid = threadIdx.x;
    for (int idx = tid; idx < F_OUT * F_IN; idx += 256) {
        Wl[idx >> 5][idx & 31] = W[idx];
    }
    int node0 = blockIdx.x * 4;
    if (tid < 4 * F_IN) {
        int n = tid >> 5, f = tid & 31;
        int node = node0 + n;
        float v = 0.0f;
        if (node < N)
            v = (f < 16) ? (float)h0[node * 16 + f] : (float)h1[node * 16 + (f - 16)];
        hl[n][f] = v;
    }
    __syncthreads();
    int n = tid >> 6;
    int o = tid & 63;
    int node = node0 + n;
    if (node < N) {
        float acc = b[o];
#pragma unroll
        for (int f = 0; f < F_IN; ++f) acc += hl[n][f] * Wl[o][f];
        out[node * F_OUT + o] = acc;
    }
}

extern "C" void kernel_launch(void* const* d_in, const int* in_sizes, int n_in,
                              void* d_out, int out_size, void* d_ws, size_t ws_size,
                              hipStream_t stream) {
    const float* x  = (const float*)d_in[0];
    const int*   ei = (const int*)d_in[1];   // [2,E] int32: src row then dst row
    const float* W  = (const float*)d_in[2];
    const float* b  = (const float*)d_in[3];
    float* out = (float*)d_out;

    const int N = in_sizes[0] / F_IN;
    const int E = in_sizes[1] / 2;
    const int NBKT = (N + BKT - 1) >> BKT_SHIFT;  // 196

    // d_ws: bcount(MAXB) | colbase(MAXB+1) | gcursor(MAXB) | rp(N+1) | dinv(N) |
    //       P0 P1 Q0 Q1 R0 R1 (each N*16 fp16 = 3.2MB)
    int*   bcount  = (int*)d_ws;
    int*   colbase = bcount + MAXB;
    int*   gcursor = colbase + MAXB + 1;
    int*   rp      = gcursor + MAXB;
    float* dinv    = (float*)(rp + N + 1);
    _Float16* P0   = (_Float16*)(((uintptr_t)(dinv + N) + 255) & ~(uintptr_t)255);
    size_t HSZ = (size_t)N * 16;
    _Float16* P1 = P0 + HSZ;
    _Float16* Q0 = P1 + HSZ;
    _Float16* Q1 = Q0 + HSZ;
    _Float16* R0 = Q1 + HSZ;
    _Float16* R1 = R0 + HSZ;

    // d_out scratch: binned (E uint = 6.4MB, dies after fill3) | free | col at +12.8MB.
    unsigned* binned = (unsigned*)d_out;
    int*      col    = (int*)(out + (size_t)N * F_IN);

    const int B = 256;
    dim3 blk(B);
    dim3 gEPB((E + EPB - 1) / EPB);

    hipMemsetAsync(bcount, 0, MAXB * sizeof(int), stream);

    // bucket histogram + scan -> bases/cursors; bin edges (coalesced packed writes)
    k_bucket_hist<<<gEPB, blk, 0, stream>>>(ei + E, bcount, E);
    k_scan_buckets<<<dim3(1), dim3(MAXB), 0, stream>>>(bcount, colbase, gcursor);
    k_bin<<<gEPB, blk, 0, stream>>>(ei, gcursor, binned, E);

    // per-bucket counting sort: deg/dinv/rp/col, all XCD-local writes
    k_fill3<<<dim3(NBKT), dim3(512), 0, stream>>>(binned, colbase, dinv, rp, col, N);

    // pre-scale + feature split: P = fp16(dinv .* x)
    const int N8 = N * 8;
    k_prescale<<<dim3((N8 + B - 1) / B), blk, 0, stream>>>((const f4*)x, dinv,
                                                           (h4*)P0, (h4*)P1, N8);

    // hops, one 16-feature half at a time (L2-resident read set):
    // P -> Q -> R -> P; final lands in P for k_linear.
    dim3 gHop(((size_t)N * 4 + B - 1) / B);
    k_hop_pass<<<gHop, blk, 0, stream>>>(rp, col, dinv, (const h4*)P0, (h4*)Q0, N, 0);
    k_hop_pass<<<gHop, blk, 0, stream>>>(rp, col, dinv, (const h4*)P1, (h4*)Q1, N, 0);
    k_hop_pass<<<gHop, blk, 0, stream>>>(rp, col, dinv, (const h4*)Q0, (h4*)R0, N, 0);
    k_hop_pass<<<gHop, blk, 0, stream>>>(rp, col, dinv, (const h4*)Q1, (h4*)R1, N, 0);
    k_hop_pass<<<gHop, blk, 0, stream>>>(rp, col, dinv, (const h4*)R0, (h4*)P0, N, 1);
    k_hop_pass<<<gHop, blk, 0, stream>>>(rp, col, dinv, (const h4*)R1, (h4*)P1, N, 1);

    // linear: [P0|P1] @ W^T + b -> out
    k_linear<<<dim3((N + 3) / 4), blk, 0, stream>>>(P0, P1, W, b, out, N);
}

// Round 10
// 238.657 us; speedup vs baseline: 1.2383x; 1.2383x over previous
//
#include <hip/hip_runtime.h>

// SGConv: K=3 hops of \hat{A} x (symmetric gcn_norm w/ self-loops), then Linear.
// N=100000, E=1600000, F_in=32, F_out=64.
// Round 10: R9 (2x 16-feature passes) regressed +64us -> hop cost is per-random-
// TOUCH, not per-byte (1.6M touches/hop is the floor; 6 passes doubled it).
// Revert to R8 single-pass fp16 (3x1.6M touches, 231us) and raise touch issue
// rate: 16B/lane dwordx4 gathers (4 lanes/row -> 16 lines/wave-load, 2x
// outstanding lines, half the load instructions). col loads nontemporal.

#define F_IN 32
#define F_OUT 64
#define BKT_SHIFT 9                  // 512 nodes per dst-bucket
#define BKT (1 << BKT_SHIFT)
#define EPB 4096                     // edges per binning/histogram block
#define MAXB 256                     // >= number of buckets (196 for N=100000)

typedef float f4 __attribute__((ext_vector_type(4)));
typedef float f8 __attribute__((ext_vector_type(8)));
typedef _Float16 h4 __attribute__((ext_vector_type(4)));   // 8B
typedef _Float16 h8 __attribute__((ext_vector_type(8)));   // 16B

// Per-block LDS histogram of dst-buckets -> MAXB global atomics per block.
__global__ __launch_bounds__(256) void k_bucket_hist(const int* __restrict__ dst,
                                                     int* __restrict__ bcount, int E) {
    __shared__ int h[MAXB];
    int tid = threadIdx.x;
    h[tid] = 0;
    __syncthreads();
    int base = blockIdx.x * EPB;
    for (int k = 0; k < EPB / 256; ++k) {
        int i = base + k * 256 + tid;
        if (i < E) atomicAdd(&h[dst[i] >> BKT_SHIFT], 1);
    }
    __syncthreads();
    if (h[tid]) atomicAdd(&bcount[tid], h[tid]);
}

// One block (MAXB threads): exclusive scan of bucket counts.
__global__ __launch_bounds__(MAXB) void k_scan_buckets(const int* __restrict__ bcount,
                                                       int* __restrict__ colbase,
                                                       int* __restrict__ gcursor) {
    __shared__ int sc[MAXB];
    int tid = threadIdx.x;
    int c = bcount[tid];
    sc[tid] = c;
    __syncthreads();
    for (int off = 1; off < MAXB; off <<= 1) {
        int t = (tid >= off) ? sc[tid - off] : 0;
        __syncthreads();
        sc[tid] += t;
        __syncthreads();
    }
    int excl = sc[tid] - c;
    colbase[tid] = excl;
    gcursor[tid] = excl;
    if (tid == MAXB - 1) colbase[MAXB] = sc[tid];
}

// Bin edges into dst-buckets; records packed to 4B: (src << 9) | (dst & 511).
// shfl two-level scan over the 256 LDS counters.
__global__ __launch_bounds__(256) void k_bin(const int* __restrict__ ei,
                                             int* __restrict__ gcursor,
                                             unsigned* __restrict__ binned, int E) {
    __shared__ unsigned stage[EPB];          // 16 KB
    __shared__ unsigned char bid[EPB];       // 4 KB
    __shared__ int hist[MAXB], lscan[MAXB], lbase[MAXB], fcur[MAXB];
    __shared__ int wsum[4];
    int tid = threadIdx.x;
    int base = blockIdx.x * EPB;
    int cnt = E - base; if (cnt > EPB) cnt = EPB;

    hist[tid] = 0;
    __syncthreads();
    for (int k = 0; k < EPB / 256; ++k) {
        int i = base + k * 256 + tid;
        if (i < E) atomicAdd(&hist[ei[E + i] >> BKT_SHIFT], 1);
    }
    __syncthreads();
    {
        int c = hist[tid];
        int lane = tid & 63, wid = tid >> 6;
        int inc = c;
#pragma unroll
        for (int off = 1; off < 64; off <<= 1) {
            int t = __shfl_up(inc, off);
            if (lane >= off) inc += t;
        }
        if (lane == 63) wsum[wid] = inc;
        __syncthreads();
        if (wid == 0) {
            int v = (lane < 4) ? wsum[lane] : 0;
#pragma unroll
            for (int off = 1; off < 4; off <<= 1) {
                int t = __shfl_up(v, off);
                if (lane >= off) v += t;
            }
            if (lane < 4) wsum[lane] = v;
        }
        __syncthreads();
        int excl = inc + (wid ? wsum[wid - 1] : 0) - c;
        lscan[tid] = excl;
        fcur[tid] = excl;
        lbase[tid] = c ? atomicAdd(&gcursor[tid], c) : 0;
    }
    __syncthreads();
    for (int k = 0; k < EPB / 256; ++k) {
        int i = base + k * 256 + tid;
        if (i < E) {
            unsigned s = (unsigned)ei[i];
            unsigned d = (unsigned)ei[E + i];
            int b = d >> BKT_SHIFT;
            int loc = atomicAdd(&fcur[b], 1);
            stage[loc] = (s << BKT_SHIFT) | (d & (BKT - 1));
            bid[loc] = (unsigned char)b;
        }
    }
    __syncthreads();
    for (int k = 0; k < EPB / 256; ++k) {
        int idx = k * 256 + tid;
        if (idx < cnt) {
            int b = bid[idx];
            binned[lbase[b] + (idx - lscan[b])] = stage[idx];
        }
    }
}

// One workgroup (512 thr) per 512-node bucket: LDS hist -> shfl scan ->
// dinv/rp (coalesced) -> col scatter via LDS cursors. No global atomics.
__global__ __launch_bounds__(512) void k_fill3(const unsigned* __restrict__ binned,
                                               const int* __restrict__ colbase,
                                               float* __restrict__ dinv,
                                               int* __restrict__ rp,
                                               int* __restrict__ col, int N) {
    __shared__ int h[BKT];
    __shared__ int wsum[8];
    int tid = threadIdx.x;
    int b = blockIdx.x;
    int base_node = b << BKT_SHIFT;
    int cbase = colbase[b];
    int cend  = colbase[b + 1];

    h[tid] = 0;
    __syncthreads();
    for (int e = cbase + tid; e < cend; e += 512)
        atomicAdd(&h[binned[e] & (BKT - 1)], 1);
    __syncthreads();

    int deg = h[tid];
    int lane = tid & 63, wid = tid >> 6;
    int inc = deg;
#pragma unroll
    for (int off = 1; off < 64; off <<= 1) {
        int t = __shfl_up(inc, off);
        if (lane >= off) inc += t;
    }
    if (lane == 63) wsum[wid] = inc;
    __syncthreads();
    if (wid == 0) {
        int v = (lane < 8) ? wsum[lane] : 0;
#pragma unroll
        for (int off = 1; off < 8; off <<= 1) {
            int t = __shfl_up(v, off);
            if (lane >= off) v += t;
        }
        if (lane < 8) wsum[lane] = v;
    }
    __syncthreads();
    int incl = inc + (wid ? wsum[wid - 1] : 0);
    int excl = incl - deg;

    int node = base_node + tid;
    if (node < N) {
        dinv[node] = rsqrtf(1.0f + (float)deg);
        rp[node + 1] = cbase + incl;
    }
    h[tid] = excl;
    if (b == 0 && tid == 0) rp[0] = 0;
    __syncthreads();

    for (int e = cbase + tid; e < cend; e += 512) {
        unsigned r = binned[e];
        int slot = cbase + atomicAdd(&h[r & (BKT - 1)], 1);
        col[slot] = (int)(r >> BKT_SHIFT);
    }
}

// g0 = fp16(dinv .* x): read f4, write h4 (row-major, same layout h8 reads).
__global__ void k_prescale(const f4* __restrict__ x, const float* __restrict__ dinv,
                           h4* __restrict__ g, int N8) {
    int t = blockIdx.x * blockDim.x + threadIdx.x;
    if (t < N8) {
        f4 v = dinv[t >> 3] * x[t];
        g[t] = __builtin_convertvector(v, h4);
    }
}

// One hop on pre-scaled fp16 state, fp32 accumulate.
// 4 lanes/row x 16B dwordx4 gathers -> 16 random lines per wave-load, unroll-4.
__global__ __launch_bounds__(256) void k_hop_gather(const int* __restrict__ rp,
                                                    const int* __restrict__ col,
                                                    const float* __restrict__ dinv,
                                                    const h8* __restrict__ gin,
                                                    h8* __restrict__ gout,
                                                    int N, int final_hop) {
    int t = blockIdx.x * blockDim.x + threadIdx.x;
    int n = t >> 2;
    if (n >= N) return;
    int q = t & 3;
    int e0 = rp[n], e1 = rp[n + 1];
    f8 a0 = __builtin_convertvector(gin[n * 4 + q], f8);  // self-loop term
    f8 a1 = {0.f, 0.f, 0.f, 0.f, 0.f, 0.f, 0.f, 0.f};
    int e = e0;
    for (; e + 3 < e1; e += 4) {
        int s0 = __builtin_nontemporal_load(col + e);
        int s1 = __builtin_nontemporal_load(col + e + 1);
        int s2 = __builtin_nontemporal_load(col + e + 2);
        int s3 = __builtin_nontemporal_load(col + e + 3);
        h8 h0 = gin[s0 * 4 + q];
        h8 h1 = gin[s1 * 4 + q];
        h8 h2 = gin[s2 * 4 + q];
        h8 h3 = gin[s3 * 4 + q];
        a0 += __builtin_convertvector(h0, f8);
        a1 += __builtin_convertvector(h1, f8);
        a0 += __builtin_convertvector(h2, f8);
        a1 += __builtin_convertvector(h3, f8);
    }
    for (; e < e1; ++e)
        a0 += __builtin_convertvector(gin[__builtin_nontemporal_load(col + e) * 4 + q], f8);
    float di = dinv[n];
    float sc = final_hop ? di : di * di;
    f8 r = sc * (a0 + a1);
    gout[n * 4 + q] = __builtin_convertvector(r, h8);
}

// out[n][o] = b[o] + sum_f h[n][f] * W[o][f]; h is fp16.
__global__ __launch_bounds__(256) void k_linear(const _Float16* __restrict__ h,
                                                const float* __restrict__ W,
                                                const float* __restrict__ b,
                                                float* __restrict__ out, int N) {
    __shared__ float Wl[F_OUT][F_IN + 1];
    __shared__ float hl[4][F_IN];
    int tid = threadIdx.x;
    for (int idx = tid; idx < F_OUT * F_IN; idx += 256) {
        Wl[idx >> 5][idx & 31] = W[idx];
    }
    int node0 = blockIdx.x * 4;
    if (tid < 4 * F_IN) {
        int n = tid >> 5, f = tid & 31;
        int node = node0 + n;
        hl[n][f] = (node < N) ? (float)h[node * F_IN + f] : 0.0f;
    }
    __syncthreads();
    int n = tid >> 6;
    int o = tid & 63;
    int node = node0 + n;
    if (node < N) {
        float acc = b[o];
#pragma unroll
        for (int f = 0; f < F_IN; ++f) acc += hl[n][f] * Wl[o][f];
        out[node * F_OUT + o] = acc;
    }
}

extern "C" void kernel_launch(void* const* d_in, const int* in_sizes, int n_in,
                              void* d_out, int out_size, void* d_ws, size_t ws_size,
                              hipStream_t stream) {
    const float* x  = (const float*)d_in[0];
    const int*   ei = (const int*)d_in[1];   // [2,E] int32: src row then dst row
    const float* W  = (const float*)d_in[2];
    const float* b  = (const float*)d_in[3];
    float* out = (float*)d_out;

    const int N = in_sizes[0] / F_IN;
    const int E = in_sizes[1] / 2;
    const int NBKT = (N + BKT - 1) >> BKT_SHIFT;  // 196

    // d_ws: bcount(MAXB) | colbase(MAXB+1) | gcursor(MAXB) | rp(N+1) | dinv(N) |
    //       hA (N*32 fp16 = 6.4MB) | hB2 (N*32 fp16)
    int*   bcount  = (int*)d_ws;
    int*   colbase = bcount + MAXB;
    int*   gcursor = colbase + MAXB + 1;
    int*   rp      = gcursor + MAXB;
    float* dinv    = (float*)(rp + N + 1);
    _Float16* hA   = (_Float16*)(((uintptr_t)(dinv + N) + 255) & ~(uintptr_t)255);
    _Float16* hB2  = hA + (size_t)N * F_IN;

    // d_out scratch: binned (E uint = 6.4MB; dies after fill3, reused as hB fp16) |
    // col (E int = 6.4MB at +12.8MB). k_linear finally owns d_out.
    unsigned* binned = (unsigned*)d_out;
    _Float16* hB     = (_Float16*)d_out;
    int*      col    = (int*)(out + (size_t)N * F_IN);

    const int B = 256;
    dim3 blk(B);
    dim3 gEPB((E + EPB - 1) / EPB);

    hipMemsetAsync(bcount, 0, MAXB * sizeof(int), stream);

    // bucket histogram + scan -> bases/cursors; bin edges (coalesced packed writes)
    k_bucket_hist<<<gEPB, blk, 0, stream>>>(ei + E, bcount, E);
    k_scan_buckets<<<dim3(1), dim3(MAXB), 0, stream>>>(bcount, colbase, gcursor);
    k_bin<<<gEPB, blk, 0, stream>>>(ei, gcursor, binned, E);

    // per-bucket counting sort: deg/dinv/rp/col, all XCD-local writes
    k_fill3<<<dim3(NBKT), dim3(512), 0, stream>>>(binned, colbase, dinv, rp, col, N);

    // pre-scale: g0 = fp16(dinv .* x) -> hA (ws; binned still live until fill3 done)
    const int N8 = N * 8;
    k_prescale<<<dim3((N8 + B - 1) / B), blk, 0, stream>>>((const f4*)x, dinv, (h4*)hA, N8);

    // hops: hA -> hB(d_out) -> hB2(ws) -> hA(ws); final in ws for k_linear.
    dim3 gHop(((size_t)N * 4 + B - 1) / B);
    k_hop_gather<<<gHop, blk, 0, stream>>>(rp, col, dinv, (const h8*)hA, (h8*)hB, N, 0);
    k_hop_gather<<<gHop, blk, 0, stream>>>(rp, col, dinv, (const h8*)hB, (h8*)hB2, N, 0);
    k_hop_gather<<<gHop, blk, 0, stream>>>(rp, col, dinv, (const h8*)hB2, (h8*)hA, N, 1);

    // linear: hA @ W^T + b -> out
    k_linear<<<dim3((N + 3) / 4), blk, 0, stream>>>(hA, W, b, out, N);
}

// Round 12
// 223.612 us; speedup vs baseline: 1.3217x; 1.0673x over previous
//
#include <hip/hip_runtime.h>

// SGConv: K=3 hops of \hat{A} x (symmetric gcn_norm w/ self-loops), then Linear.
// N=100000, E=1600000, F_in=32, F_out=64.
// Round 12: R11 failed from slab overflow — supers 0..11 hold exactly 8192
// nodes -> mean edge count 131072 == old SCAP (sd ~347), so ~half the supers
// spilled into the next slab. SCAP -> 147456 (+47 sd). Everything else is
// R11 unchanged: two-level radix partition (L1: 13 supers of 8192 nodes,
// L2: 16 subs of 512), slab self-reservation, rp as int2 (start,end),
// LDS-staged fill3, R8-config hops (8 lanes/row h4).

#define F_IN 32
#define F_OUT 64
#define SB_SHIFT 13                  // 8192 nodes per super-bucket
#define MAXSB 16
#define SUB_SHIFT 9                  // 512 nodes per sub-bucket
#define SUB (1 << SUB_SHIFT)
#define EPB1 2048
#define EPB2 4096
#define SCAP 147456                  // super slab cap (mean 131072, sd ~347: +47 sd)
#define SUBCAP 12288                 // sub slab cap (mean 8192, sd ~90: +45 sd)
#define BPS (SCAP / EPB2)            // 36 blocks per super in k_bin2

typedef float f4 __attribute__((ext_vector_type(4)));
typedef _Float16 h4 __attribute__((ext_vector_type(4)));   // 8B
typedef int i2 __attribute__((ext_vector_type(2)));

// Level-1 bin: 13 super-buckets, LDS-staged, ~630B coalesced runs.
__global__ __launch_bounds__(256) void k_bin1(const int* __restrict__ ei,
                                              int* __restrict__ scur,
                                              unsigned* __restrict__ b1, int E) {
    __shared__ unsigned stage[EPB1];         // 8 KB
    __shared__ unsigned char bid[EPB1];      // 2 KB
    __shared__ int hist[MAXSB], lscan[MAXSB], lbase[MAXSB], fcur[MAXSB];
    int tid = threadIdx.x;
    int base = blockIdx.x * EPB1;
    int cnt = E - base; if (cnt > EPB1) cnt = EPB1;

    if (tid < MAXSB) hist[tid] = 0;
    __syncthreads();
    for (int k = 0; k < EPB1 / 256; ++k) {
        int i = base + k * 256 + tid;
        if (i < E) atomicAdd(&hist[ei[E + i] >> SB_SHIFT], 1);
    }
    __syncthreads();
    if (tid < 64) {
        int c = (tid < MAXSB) ? hist[tid] : 0;
        int inc = c;
#pragma unroll
        for (int off = 1; off < MAXSB; off <<= 1) {
            int t = __shfl_up(inc, off);
            if (tid >= off) inc += t;
        }
        if (tid < MAXSB) {
            lscan[tid] = inc - c;
            fcur[tid] = inc - c;
            lbase[tid] = c ? atomicAdd(&scur[tid], c) : 0;
        }
    }
    __syncthreads();
    for (int k = 0; k < EPB1 / 256; ++k) {
        int i = base + k * 256 + tid;
        if (i < E) {
            unsigned s = (unsigned)ei[i];
            unsigned d = (unsigned)ei[E + i];
            int b = d >> SB_SHIFT;
            int loc = atomicAdd(&fcur[b], 1);
            stage[loc] = (s << SB_SHIFT) | (d & ((1u << SB_SHIFT) - 1));
            bid[loc] = (unsigned char)b;
        }
    }
    __syncthreads();
    for (int k = 0; k < EPB1 / 256; ++k) {
        int idx = k * 256 + tid;
        if (idx < cnt) {
            int b = bid[idx];
            b1[(size_t)b * SCAP + lbase[b] + (idx - lscan[b])] = stage[idx];
        }
    }
}

// Level-2 bin: split one super-slab chunk into its 16 sub-buckets (~1KB runs).
__global__ __launch_bounds__(256) void k_bin2(const unsigned* __restrict__ b1,
                                              const int* __restrict__ scur,
                                              int* __restrict__ subcur,
                                              unsigned* __restrict__ b2) {
    int sb = blockIdx.x / BPS;
    int base = (blockIdx.x % BPS) * EPB2;
    int count = scur[sb];
    if (base >= count) return;
    int cnt = count - base; if (cnt > EPB2) cnt = EPB2;
    const unsigned* src = b1 + (size_t)sb * SCAP + base;

    __shared__ unsigned stage[EPB2];         // 16 KB
    __shared__ unsigned char bid[EPB2];      // 4 KB
    __shared__ int hist[16], lscan[16], lbase[16], fcur[16];
    int tid = threadIdx.x;
    if (tid < 16) hist[tid] = 0;
    __syncthreads();
    for (int k = 0; k < EPB2 / 256; ++k) {
        int i = k * 256 + tid;
        if (i < cnt) atomicAdd(&hist[(src[i] >> SUB_SHIFT) & 15], 1);
    }
    __syncthreads();
    if (tid < 64) {
        int c = (tid < 16) ? hist[tid] : 0;
        int inc = c;
#pragma unroll
        for (int off = 1; off < 16; off <<= 1) {
            int t = __shfl_up(inc, off);
            if (tid >= off) inc += t;
        }
        if (tid < 16) {
            lscan[tid] = inc - c;
            fcur[tid] = inc - c;
            lbase[tid] = c ? atomicAdd(&subcur[sb * 16 + tid], c) : 0;
        }
    }
    __syncthreads();
    for (int k = 0; k < EPB2 / 256; ++k) {
        int i = k * 256 + tid;
        if (i < cnt) {
            unsigned r = src[i];
            int b = (r >> SUB_SHIFT) & 15;
            int loc = atomicAdd(&fcur[b], 1);
            stage[loc] = ((r >> SB_SHIFT) << SUB_SHIFT) | (r & (SUB - 1));
            bid[loc] = (unsigned char)b;
        }
    }
    __syncthreads();
    for (int k = 0; k < EPB2 / 256; ++k) {
        int idx = k * 256 + tid;
        if (idx < cnt) {
            int b = bid[idx];
            b2[(size_t)(sb * 16 + b) * SUBCAP + lbase[b] + (idx - lscan[b])] = stage[idx];
        }
    }
}

// One workgroup per 512-node sub-bucket: stage slab in LDS (one global read),
// hist -> shfl scan -> dinv + rp2(start,end) -> col scatter. Single-owner writes.
__global__ __launch_bounds__(512) void k_fill3(const unsigned* __restrict__ b2,
                                               const int* __restrict__ subcur,
                                               float* __restrict__ dinv,
                                               i2* __restrict__ rp2,
                                               int* __restrict__ col, int N) {
    __shared__ unsigned stage[SUBCAP];       // 48 KB
    __shared__ int h[SUB];
    __shared__ int wsum[8];
    int tid = threadIdx.x;
    int g = blockIdx.x;
    int count = subcur[g];
    int sbase = g * SUBCAP;

    h[tid] = 0;
    for (int e = tid; e < count; e += 512) stage[e] = b2[(size_t)sbase + e];
    __syncthreads();
    for (int e = tid; e < count; e += 512) atomicAdd(&h[stage[e] & (SUB - 1)], 1);
    __syncthreads();

    int deg = h[tid];
    int lane = tid & 63, wid = tid >> 6;
    int inc = deg;
#pragma unroll
    for (int off = 1; off < 64; off <<= 1) {
        int t = __shfl_up(inc, off);
        if (lane >= off) inc += t;
    }
    if (lane == 63) wsum[wid] = inc;
    __syncthreads();
    if (wid == 0) {
        int v = (lane < 8) ? wsum[lane] : 0;
#pragma unroll
        for (int off = 1; off < 8; off <<= 1) {
            int t = __shfl_up(v, off);
            if (lane >= off) v += t;
        }
        if (lane < 8) wsum[lane] = v;
    }
    __syncthreads();
    int incl = inc + (wid ? wsum[wid - 1] : 0);
    int excl = incl - deg;

    int node = (g << SUB_SHIFT) + tid;
    if (node < N) {
        dinv[node] = rsqrtf(1.0f + (float)deg);
        rp2[node] = (i2){sbase + excl, sbase + incl};
    }
    h[tid] = excl;
    __syncthreads();

    for (int e = tid; e < count; e += 512) {
        unsigned r = stage[e];
        int slot = sbase + atomicAdd(&h[r & (SUB - 1)], 1);
        col[slot] = (int)(r >> SUB_SHIFT);
    }
}

// g0 = fp16(dinv .* x)
__global__ void k_prescale(const f4* __restrict__ x, const float* __restrict__ dinv,
                           h4* __restrict__ g, int N8) {
    int t = blockIdx.x * blockDim.x + threadIdx.x;
    if (t < N8) {
        f4 v = dinv[t >> 3] * x[t];
        g[t] = __builtin_convertvector(v, h4);
    }
}

// One hop on pre-scaled fp16 state, fp32 accumulate (R8 config, rp as int2).
__global__ __launch_bounds__(256) void k_hop_gather(const i2* __restrict__ rp2,
                                                    const int* __restrict__ col,
                                                    const float* __restrict__ dinv,
                                                    const h4* __restrict__ gin,
                                                    h4* __restrict__ gout,
                                                    int N, int final_hop) {
    int t = blockIdx.x * blockDim.x + threadIdx.x;
    int n = t >> 3;
    if (n >= N) return;
    int q = t & 7;
    i2 r2 = rp2[n];
    int e0 = r2.x, e1 = r2.y;
    f4 a0 = __builtin_convertvector(gin[n * 8 + q], f4);  // self-loop term
    f4 a1 = {0.f, 0.f, 0.f, 0.f};
    int e = e0;
    for (; e + 3 < e1; e += 4) {
        int s0 = col[e], s1 = col[e + 1], s2 = col[e + 2], s3 = col[e + 3];
        h4 h0 = gin[s0 * 8 + q];
        h4 h1 = gin[s1 * 8 + q];
        h4 h2 = gin[s2 * 8 + q];
        h4 h3 = gin[s3 * 8 + q];
        a0 += __builtin_convertvector(h0, f4);
        a1 += __builtin_convertvector(h1, f4);
        a0 += __builtin_convertvector(h2, f4);
        a1 += __builtin_convertvector(h3, f4);
    }
    for (; e < e1; ++e) a0 += __builtin_convertvector(gin[col[e] * 8 + q], f4);
    float di = dinv[n];
    float sc = final_hop ? di : di * di;
    f4 r = sc * (a0 + a1);
    gout[n * 8 + q] = __builtin_convertvector(r, h4);
}

// out[n][o] = b[o] + sum_f h[n][f] * W[o][f]; h is fp16.
__global__ __launch_bounds__(256) void k_linear(const _Float16* __restrict__ h,
                                                const float* __restrict__ W,
                                                const float* __restrict__ b,
                                                float* __restrict__ out, int N) {
    __shared__ float Wl[F_OUT][F_IN + 1];
    __shared__ float hl[4][F_IN];
    int tid = threadIdx.x;
    for (int idx = tid; idx < F_OUT * F_IN; idx += 256) {
        Wl[idx >> 5][idx & 31] = W[idx];
    }
    int node0 = blockIdx.x * 4;
    if (tid < 4 * F_IN) {
        int n = tid >> 5, f = tid & 31;
        int node = node0 + n;
        hl[n][f] = (node < N) ? (float)h[node * F_IN + f] : 0.0f;
    }
    __syncthreads();
    int n = tid >> 6;
    int o = tid & 63;
    int node = node0 + n;
    if (node < N) {
        float acc = b[o];
#pragma unroll
        for (int f = 0; f < F_IN; ++f) acc += hl[n][f] * Wl[o][f];
        out[node * F_OUT + o] = acc;
    }
}

extern "C" void kernel_launch(void* const* d_in, const int* in_sizes, int n_in,
                              void* d_out, int out_size, void* d_ws, size_t ws_size,
                              hipStream_t stream) {
    const float* x  = (const float*)d_in[0];
    const int*   ei = (const int*)d_in[1];   // [2,E] int32: src row then dst row
    const float* W  = (const float*)d_in[2];
    const float* b  = (const float*)d_in[3];
    float* out = (float*)d_out;

    const int N = in_sizes[0] / F_IN;
    const int E = in_sizes[1] / 2;
    const int NSB  = (N + (1 << SB_SHIFT) - 1) >> SB_SHIFT;   // 13
    const int NSUB = (N + SUB - 1) >> SUB_SHIFT;              // 196

    // Everything scratch lives in ws (256MB):
    // scur(MAXSB) | subcur(MAXSB*16) | rp2(2N) | dinv(N) | b1 | b2 | col | hA hB hB2
    int* scur   = (int*)d_ws;
    int* subcur = scur + MAXSB;
    i2*  rp2    = (i2*)(subcur + MAXSB * 16);
    float* dinv = (float*)(rp2 + N);
    unsigned* b1 = (unsigned*)(((uintptr_t)(dinv + N) + 255) & ~(uintptr_t)255);
    unsigned* b2 = b1 + (size_t)MAXSB * SCAP;
    int* col     = (int*)(b2 + (size_t)MAXSB * 16 * SUBCAP);
    _Float16* hA = (_Float16*)(((uintptr_t)(col + (size_t)MAXSB * 16 * SUBCAP) + 255)
                               & ~(uintptr_t)255);
    _Float16* hB  = hA + (size_t)N * F_IN;
    _Float16* hB2 = hB + (size_t)N * F_IN;

    const int B = 256;
    dim3 blk(B);

    hipMemsetAsync(scur, 0, (MAXSB + MAXSB * 16) * sizeof(int), stream);

    // two-level radix partition (coalesced line-sized runs everywhere)
    k_bin1<<<dim3((E + EPB1 - 1) / EPB1), blk, 0, stream>>>(ei, scur, b1, E);
    k_bin2<<<dim3(NSB * BPS), blk, 0, stream>>>(b1, scur, subcur, b2);

    // per-sub-bucket counting sort: dinv/rp2/col, LDS-staged, single-owner writes
    k_fill3<<<dim3(NSUB), dim3(512), 0, stream>>>(b2, subcur, dinv, rp2, col, N);

    // pre-scale: g0 = fp16(dinv .* x) -> hA
    const int N8 = N * 8;
    k_prescale<<<dim3((N8 + B - 1) / B), blk, 0, stream>>>((const f4*)x, dinv, (h4*)hA, N8);

    // hops: hA -> hB -> hB2 -> hA
    dim3 gHop(((size_t)N * 8 + B - 1) / B);
    k_hop_gather<<<gHop, blk, 0, stream>>>(rp2, col, dinv, (const h4*)hA, (h4*)hB, N, 0);
    k_hop_gather<<<gHop, blk, 0, stream>>>(rp2, col, dinv, (const h4*)hB, (h4*)hB2, N, 0);
    k_hop_gather<<<gHop, blk, 0, stream>>>(rp2, col, dinv, (const h4*)hB2, (h4*)hA, N, 1);

    // linear: hA @ W^T + b -> out
    k_linear<<<dim3((N + 3) / 4), blk, 0, stream>>>(hA, W, b, out, N);
}

// Round 13
// 212.255 us; speedup vs baseline: 1.3924x; 1.0535x over previous
//
#include <hip/hip_runtime.h>

// SGConv: K=3 hops of \hat{A} x (symmetric gcn_norm w/ self-loops), then Linear.
// N=100000, E=1600000, F_in=32, F_out=64.
// Round 13 (from R12 @ 223.6us): hops are at the random-line-touch wall
// (~39us each, bytes don't matter). Cut known build/epilogue fat:
//  1) fuse linear into hop3 (kill 6.4MB write + 6.4MB read + 1 launch)
//  2) register-cache records in bin1/bin2 (kill 12.8MB of phase-3 re-reads)
//  3) drop bin2's bid[] LDS (stage unpacked rec, repack at write-out)
// If neutral -> non-hop residue is launch gaps -> next: cooperative fusion.

#define F_IN 32
#define F_OUT 64
#define SB_SHIFT 13                  // 8192 nodes per super-bucket
#define MAXSB 16
#define SUB_SHIFT 9                  // 512 nodes per sub-bucket
#define SUB (1 << SUB_SHIFT)
#define EPB1 2048
#define EPB2 4096
#define SCAP 147456                  // super slab cap (mean 131072, sd ~347)
#define SUBCAP 12288                 // sub slab cap (mean 8192, sd ~90)
#define BPS (SCAP / EPB2)            // 36 blocks per super in k_bin2

typedef float f4 __attribute__((ext_vector_type(4)));
typedef _Float16 h4 __attribute__((ext_vector_type(4)));   // 8B
typedef int i2 __attribute__((ext_vector_type(2)));

// Level-1 bin: 13 super-buckets, LDS-staged, records cached in registers.
__global__ __launch_bounds__(256) void k_bin1(const int* __restrict__ ei,
                                              int* __restrict__ scur,
                                              unsigned* __restrict__ b1, int E) {
    __shared__ unsigned stage[EPB1];         // 8 KB
    __shared__ unsigned char bidl[EPB1];     // 2 KB
    __shared__ int hist[MAXSB], lscan[MAXSB], lbase[MAXSB], fcur[MAXSB];
    unsigned rec[EPB1 / 256];
    int      bk[EPB1 / 256];
    int tid = threadIdx.x;
    int base = blockIdx.x * EPB1;
    int cnt = E - base; if (cnt > EPB1) cnt = EPB1;

    if (tid < MAXSB) hist[tid] = 0;
    __syncthreads();
#pragma unroll
    for (int k = 0; k < EPB1 / 256; ++k) {
        int i = base + k * 256 + tid;
        bk[k] = -1;
        if (i < E) {
            unsigned s = (unsigned)ei[i];
            unsigned d = (unsigned)ei[E + i];
            int b = d >> SB_SHIFT;
            rec[k] = (s << SB_SHIFT) | (d & ((1u << SB_SHIFT) - 1));
            bk[k] = b;
            atomicAdd(&hist[b], 1);
        }
    }
    __syncthreads();
    if (tid < 64) {
        int c = (tid < MAXSB) ? hist[tid] : 0;
        int inc = c;
#pragma unroll
        for (int off = 1; off < MAXSB; off <<= 1) {
            int t = __shfl_up(inc, off);
            if (tid >= off) inc += t;
        }
        if (tid < MAXSB) {
            lscan[tid] = inc - c;
            fcur[tid] = inc - c;
            lbase[tid] = c ? atomicAdd(&scur[tid], c) : 0;
        }
    }
    __syncthreads();
#pragma unroll
    for (int k = 0; k < EPB1 / 256; ++k) {
        if (bk[k] >= 0) {
            int loc = atomicAdd(&fcur[bk[k]], 1);
            stage[loc] = rec[k];
            bidl[loc] = (unsigned char)bk[k];
        }
    }
    __syncthreads();
    for (int k = 0; k < EPB1 / 256; ++k) {
        int idx = k * 256 + tid;
        if (idx < cnt) {
            int b = bidl[idx];
            b1[(size_t)b * SCAP + lbase[b] + (idx - lscan[b])] = stage[idx];
        }
    }
}

// Level-2 bin: split one super-slab chunk into its 16 sub-buckets.
// Records cached in registers; stage holds unpacked rec (sub recomputed at p4).
__global__ __launch_bounds__(256) void k_bin2(const unsigned* __restrict__ b1,
                                              const int* __restrict__ scur,
                                              int* __restrict__ subcur,
                                              unsigned* __restrict__ b2) {
    int sb = blockIdx.x / BPS;
    int base = (blockIdx.x % BPS) * EPB2;
    int count = scur[sb];
    if (base >= count) return;
    int cnt = count - base; if (cnt > EPB2) cnt = EPB2;
    const unsigned* src = b1 + (size_t)sb * SCAP + base;

    __shared__ unsigned stage[EPB2];         // 16 KB
    __shared__ int hist[16], lscan[16], lbase[16], fcur[16];
    unsigned rec[EPB2 / 256];
    int tid = threadIdx.x;
    if (tid < 16) hist[tid] = 0;
    __syncthreads();
#pragma unroll
    for (int k = 0; k < EPB2 / 256; ++k) {
        int i = k * 256 + tid;
        rec[k] = 0xFFFFFFFFu;
        if (i < cnt) {
            unsigned r = src[i];
            rec[k] = r;
            atomicAdd(&hist[(r >> SUB_SHIFT) & 15], 1);
        }
    }
    __syncthreads();
    if (tid < 64) {
        int c = (tid < 16) ? hist[tid] : 0;
        int inc = c;
#pragma unroll
        for (int off = 1; off < 16; off <<= 1) {
            int t = __shfl_up(inc, off);
            if (tid >= off) inc += t;
        }
        if (tid < 16) {
            lscan[tid] = inc - c;
            fcur[tid] = inc - c;
            lbase[tid] = c ? atomicAdd(&subcur[sb * 16 + tid], c) : 0;
        }
    }
    __syncthreads();
#pragma unroll
    for (int k = 0; k < EPB2 / 256; ++k) {
        if (rec[k] != 0xFFFFFFFFu) {
            int b = (rec[k] >> SUB_SHIFT) & 15;
            int loc = atomicAdd(&fcur[b], 1);
            stage[loc] = rec[k];
        }
    }
    __syncthreads();
    for (int k = 0; k < EPB2 / 256; ++k) {
        int idx = k * 256 + tid;
        if (idx < cnt) {
            unsigned r = stage[idx];
            int b = (r >> SUB_SHIFT) & 15;
            unsigned packed = ((r >> SB_SHIFT) << SUB_SHIFT) | (r & (SUB - 1));
            b2[(size_t)(sb * 16 + b) * SUBCAP + lbase[b] + (idx - lscan[b])] = packed;
        }
    }
}

// One workgroup per 512-node sub-bucket: stage slab in LDS, hist -> shfl scan ->
// dinv + rp2(start,end) -> col scatter. Single-owner writes.
__global__ __launch_bounds__(512) void k_fill3(const unsigned* __restrict__ b2,
                                               const int* __restrict__ subcur,
                                               float* __restrict__ dinv,
                                               i2* __restrict__ rp2,
                                               int* __restrict__ col, int N) {
    __shared__ unsigned stage[SUBCAP];       // 48 KB
    __shared__ int h[SUB];
    __shared__ int wsum[8];
    int tid = threadIdx.x;
    int g = blockIdx.x;
    int count = subcur[g];
    int sbase = g * SUBCAP;

    h[tid] = 0;
    for (int e = tid; e < count; e += 512) stage[e] = b2[(size_t)sbase + e];
    __syncthreads();
    for (int e = tid; e < count; e += 512) atomicAdd(&h[stage[e] & (SUB - 1)], 1);
    __syncthreads();

    int deg = h[tid];
    int lane = tid & 63, wid = tid >> 6;
    int inc = deg;
#pragma unroll
    for (int off = 1; off < 64; off <<= 1) {
        int t = __shfl_up(inc, off);
        if (lane >= off) inc += t;
    }
    if (lane == 63) wsum[wid] = inc;
    __syncthreads();
    if (wid == 0) {
        int v = (lane < 8) ? wsum[lane] : 0;
#pragma unroll
        for (int off = 1; off < 8; off <<= 1) {
            int t = __shfl_up(v, off);
            if (lane >= off) v += t;
        }
        if (lane < 8) wsum[lane] = v;
    }
    __syncthreads();
    int incl = inc + (wid ? wsum[wid - 1] : 0);
    int excl = incl - deg;

    int node = (g << SUB_SHIFT) + tid;
    if (node < N) {
        dinv[node] = rsqrtf(1.0f + (float)deg);
        rp2[node] = (i2){sbase + excl, sbase + incl};
    }
    h[tid] = excl;
    __syncthreads();

    for (int e = tid; e < count; e += 512) {
        unsigned r = stage[e];
        int slot = sbase + atomicAdd(&h[r & (SUB - 1)], 1);
        col[slot] = (int)(r >> SUB_SHIFT);
    }
}

// g0 = fp16(dinv .* x)
__global__ void k_prescale(const f4* __restrict__ x, const float* __restrict__ dinv,
                           h4* __restrict__ g, int N8) {
    int t = blockIdx.x * blockDim.x + threadIdx.x;
    if (t < N8) {
        f4 v = dinv[t >> 3] * x[t];
        g[t] = __builtin_convertvector(v, h4);
    }
}

// Mid hop (hops 1,2): R8 config, 8 lanes/row h4, fp32 accumulate.
__global__ __launch_bounds__(256) void k_hop_gather(const i2* __restrict__ rp2,
                                                    const int* __restrict__ col,
                                                    const float* __restrict__ dinv,
                                                    const h4* __restrict__ gin,
                                                    h4* __restrict__ gout, int N) {
    int t = blockIdx.x * blockDim.x + threadIdx.x;
    int n = t >> 3;
    if (n >= N) return;
    int q = t & 7;
    i2 r2 = rp2[n];
    int e0 = r2.x, e1 = r2.y;
    f4 a0 = __builtin_convertvector(gin[n * 8 + q], f4);  // self-loop term
    f4 a1 = {0.f, 0.f, 0.f, 0.f};
    int e = e0;
    for (; e + 3 < e1; e += 4) {
        int s0 = col[e], s1 = col[e + 1], s2 = col[e + 2], s3 = col[e + 3];
        h4 h0 = gin[s0 * 8 + q];
        h4 h1 = gin[s1 * 8 + q];
        h4 h2 = gin[s2 * 8 + q];
        h4 h3 = gin[s3 * 8 + q];
        a0 += __builtin_convertvector(h0, f4);
        a1 += __builtin_convertvector(h1, f4);
        a0 += __builtin_convertvector(h2, f4);
        a1 += __builtin_convertvector(h3, f4);
    }
    for (; e < e1; ++e) a0 += __builtin_convertvector(gin[col[e] * 8 + q], f4);
    float di = dinv[n];
    float sc = di * di;
    f4 r = sc * (a0 + a1);
    gout[n * 8 + q] = __builtin_convertvector(r, h4);
}

// Final hop FUSED with linear: block = 256 thr = 32 nodes x 8 lanes.
// Gather h row fragments -> LDS hl[32][33] -> block GEMM: out = h @ W^T + b.
__global__ __launch_bounds__(256) void k_hop3_linear(const i2* __restrict__ rp2,
                                                     const int* __restrict__ col,
                                                     const float* __restrict__ dinv,
                                                     const h4* __restrict__ gin,
                                                     const float* __restrict__ W,
                                                     const float* __restrict__ bias,
                                                     float* __restrict__ out, int N) {
    __shared__ float Wl[F_OUT][F_IN + 1];   // 8.4 KB
    __shared__ float hl[32][F_IN + 1];      // 4.2 KB
    int tid = threadIdx.x;
    // stage W (no sync needed before the long gather; sync below covers it)
    for (int idx = tid; idx < F_OUT * F_IN; idx += 256)
        Wl[idx >> 5][idx & 31] = W[idx];

    int nl = tid >> 3;                 // 0..31 local node
    int q = tid & 7;
    int n = blockIdx.x * 32 + nl;
    if (n < N) {
        i2 r2 = rp2[n];
        int e0 = r2.x, e1 = r2.y;
        f4 a0 = __builtin_convertvector(gin[n * 8 + q], f4);
        f4 a1 = {0.f, 0.f, 0.f, 0.f};
        int e = e0;
        for (; e + 3 < e1; e += 4) {
            int s0 = col[e], s1 = col[e + 1], s2 = col[e + 2], s3 = col[e + 3];
            h4 h0 = gin[s0 * 8 + q];
            h4 h1 = gin[s1 * 8 + q];
            h4 h2 = gin[s2 * 8 + q];
            h4 h3 = gin[s3 * 8 + q];
            a0 += __builtin_convertvector(h0, f4);
            a1 += __builtin_convertvector(h1, f4);
            a0 += __builtin_convertvector(h2, f4);
            a1 += __builtin_convertvector(h3, f4);
        }
        for (; e < e1; ++e) a0 += __builtin_convertvector(gin[col[e] * 8 + q], f4);
        float di = dinv[n];
        f4 r = di * (a0 + a1);
        hl[nl][q * 4 + 0] = r.x;
        hl[nl][q * 4 + 1] = r.y;
        hl[nl][q * 4 + 2] = r.z;
        hl[nl][q * 4 + 3] = r.w;
    }
    __syncthreads();
    // epilogue GEMM: thread t -> node nl, outputs obase..obase+7
    int obase = q * 8;
    if (n < N) {
        float acc[8];
#pragma unroll
        for (int j = 0; j < 8; ++j) acc[j] = bias[obase + j];
#pragma unroll
        for (int f = 0; f < F_IN; ++f) {
            float hv = hl[nl][f];
#pragma unroll
            for (int j = 0; j < 8; ++j) acc[j] += hv * Wl[obase + j][f];
        }
        float* op = out + (size_t)n * F_OUT + obase;
        f4 v0 = {acc[0], acc[1], acc[2], acc[3]};
        f4 v1 = {acc[4], acc[5], acc[6], acc[7]};
        *(f4*)op = v0;
        *(f4*)(op + 4) = v1;
    }
}

extern "C" void kernel_launch(void* const* d_in, const int* in_sizes, int n_in,
                              void* d_out, int out_size, void* d_ws, size_t ws_size,
                              hipStream_t stream) {
    const float* x  = (const float*)d_in[0];
    const int*   ei = (const int*)d_in[1];   // [2,E] int32: src row then dst row
    const float* W  = (const float*)d_in[2];
    const float* b  = (const float*)d_in[3];
    float* out = (float*)d_out;

    const int N = in_sizes[0] / F_IN;
    const int E = in_sizes[1] / 2;
    const int NSUB = (N + SUB - 1) >> SUB_SHIFT;              // 196

    // ws: scur(MAXSB) | subcur(MAXSB*16) | rp2(2N) | dinv(N) | b1 | b2 | col | hA hB hB2
    int* scur   = (int*)d_ws;
    int* subcur = scur + MAXSB;
    i2*  rp2    = (i2*)(subcur + MAXSB * 16);
    float* dinv = (float*)(rp2 + N);
    unsigned* b1 = (unsigned*)(((uintptr_t)(dinv + N) + 255) & ~(uintptr_t)255);
    unsigned* b2 = b1 + (size_t)MAXSB * SCAP;
    int* col     = (int*)(b2 + (size_t)MAXSB * 16 * SUBCAP);
    _Float16* hA = (_Float16*)(((uintptr_t)(col + (size_t)MAXSB * 16 * SUBCAP) + 255)
                               & ~(uintptr_t)255);
    _Float16* hB  = hA + (size_t)N * F_IN;
    _Float16* hB2 = hB + (size_t)N * F_IN;

    const int B = 256;
    dim3 blk(B);

    hipMemsetAsync(scur, 0, (MAXSB + MAXSB * 16) * sizeof(int), stream);

    // two-level radix partition
    k_bin1<<<dim3((E + EPB1 - 1) / EPB1), blk, 0, stream>>>(ei, scur, b1, E);
    k_bin2<<<dim3(((N + (1 << SB_SHIFT) - 1) >> SB_SHIFT) * BPS), blk, 0, stream>>>(
        b1, scur, subcur, b2);

    // per-sub-bucket counting sort
    k_fill3<<<dim3(NSUB), dim3(512), 0, stream>>>(b2, subcur, dinv, rp2, col, N);

    // pre-scale: g0 = fp16(dinv .* x) -> hA
    const int N8 = N * 8;
    k_prescale<<<dim3((N8 + B - 1) / B), blk, 0, stream>>>((const f4*)x, dinv, (h4*)hA, N8);

    // hops 1,2: hA -> hB -> hB2
    dim3 gHop(((size_t)N * 8 + B - 1) / B);
    k_hop_gather<<<gHop, blk, 0, stream>>>(rp2, col, dinv, (const h4*)hA, (h4*)hB, N);
    k_hop_gather<<<gHop, blk, 0, stream>>>(rp2, col, dinv, (const h4*)hB, (h4*)hB2, N);

    // hop 3 fused with linear: hB2 -> out
    k_hop3_linear<<<dim3((N + 31) / 32), blk, 0, stream>>>(rp2, col, dinv,
                                                           (const h4*)hB2, W, b, out, N);
}

// Round 14
// 202.796 us; speedup vs baseline: 1.4573x; 1.0466x over previous
//
#include <hip/hip_runtime.h>

// SGConv: K=3 hops of \hat{A} x (symmetric gcn_norm w/ self-loops), then Linear.
// N=100000, E=1600000, F_in=32, F_out=64.
// Round 14 (from R13 @ 212us): hops are at the random-touch wall (~39us each);
// attack the ~85us non-hop residue:
//  1) bin1/bin2: per-wave replicated hist+cursor (4x less LDS atomic serialization)
//  2) fill3: 256-node subs -> 391 blocks (was 196; parallelism-starved per R6)
//  3) prescale fused into fill3 (-19MB traffic, -1 launch)
//  4) hop3linear epilogue: W in registers (conflict-free (o+f)%32 LDS copy),
//     hl reads wave-uniform -> SQ_LDS_BANK_CONFLICT 5M -> ~0.

#define F_IN 32
#define F_OUT 64
#define SB_SHIFT 13                  // 8192 nodes per super-bucket
#define NSB_MAX 16
#define SUB_SHIFT 8                  // 256 nodes per sub-bucket
#define SUB (1 << SUB_SHIFT)
#define SPS 32                       // subs per super (8192/256)
#define EPB1 2048
#define EPB2 4096
#define SCAP 147456                  // super slab cap (mean 131072, sd ~347)
#define SUBCAP 6144                  // sub slab cap (mean 4096, sd ~64: +32 sd)
#define BPS (SCAP / EPB2)            // 36 blocks per super in k_bin2

typedef float f4 __attribute__((ext_vector_type(4)));
typedef _Float16 h4 __attribute__((ext_vector_type(4)));   // 8B
typedef int i2 __attribute__((ext_vector_type(2)));

// ---------- Level-1 bin: 13 supers; per-wave replicated hist/cursors ----------
__global__ __launch_bounds__(256) void k_bin1(const int* __restrict__ ei,
                                              int* __restrict__ scur,
                                              unsigned* __restrict__ b1, int E) {
    __shared__ unsigned stage[EPB1];          // 8 KB
    __shared__ unsigned char bidl[EPB1];      // 2 KB
    __shared__ int h4w[4][NSB_MAX];           // per-wave hist
    __shared__ int f4w[4][NSB_MAX];           // per-wave cursors
    __shared__ int lscanx[NSB_MAX], lbase[NSB_MAX];
    unsigned rec[EPB1 / 256];
    int      bk[EPB1 / 256];
    int tid = threadIdx.x;
    int wv = tid >> 6;
    int base = blockIdx.x * EPB1;
    int cnt = E - base; if (cnt > EPB1) cnt = EPB1;

    if (tid < 64) { h4w[tid >> 4][tid & 15] = 0; }
    __syncthreads();
#pragma unroll
    for (int k = 0; k < EPB1 / 256; ++k) {
        int i = base + k * 256 + tid;
        bk[k] = -1;
        if (i < E) {
            unsigned s = (unsigned)ei[i];
            unsigned d = (unsigned)ei[E + i];
            int b = d >> SB_SHIFT;
            rec[k] = (s << SB_SHIFT) | (d & ((1u << SB_SHIFT) - 1));
            bk[k] = b;
            atomicAdd(&h4w[wv][b], 1);
        }
    }
    __syncthreads();
    // thread b (b<16): totals, bucket scan, global reserve, per-wave bases
    if (tid < 16) {
        int t0 = h4w[0][tid], t1 = h4w[1][tid], t2 = h4w[2][tid], t3 = h4w[3][tid];
        int tot = t0 + t1 + t2 + t3;
        int inc = tot;
#pragma unroll
        for (int off = 1; off < 16; off <<= 1) {
            int t = __shfl_up(inc, off);
            if (tid >= off) inc += t;
        }
        int excl = inc - tot;
        lscanx[tid] = excl;
        lbase[tid] = tot ? atomicAdd(&scur[tid], tot) : 0;
        f4w[0][tid] = excl;
        f4w[1][tid] = excl + t0;
        f4w[2][tid] = excl + t0 + t1;
        f4w[3][tid] = excl + t0 + t1 + t2;
    }
    __syncthreads();
#pragma unroll
    for (int k = 0; k < EPB1 / 256; ++k) {
        if (bk[k] >= 0) {
            int loc = atomicAdd(&f4w[wv][bk[k]], 1);
            stage[loc] = rec[k];
            bidl[loc] = (unsigned char)bk[k];
        }
    }
    __syncthreads();
    for (int k = 0; k < EPB1 / 256; ++k) {
        int idx = k * 256 + tid;
        if (idx < cnt) {
            int b = bidl[idx];
            b1[(size_t)b * SCAP + lbase[b] + (idx - lscanx[b])] = stage[idx];
        }
    }
}

// ---------- Level-2 bin: 32 subs per super; per-wave replicated ----------
__global__ __launch_bounds__(256) void k_bin2(const unsigned* __restrict__ b1,
                                              const int* __restrict__ scur,
                                              int* __restrict__ subcur,
                                              unsigned* __restrict__ b2) {
    int sb = blockIdx.x / BPS;
    int base = (blockIdx.x % BPS) * EPB2;
    int count = scur[sb];
    if (base >= count) return;
    int cnt = count - base; if (cnt > EPB2) cnt = EPB2;
    const unsigned* src = b1 + (size_t)sb * SCAP + base;

    __shared__ unsigned stage[EPB2];          // 16 KB
    __shared__ unsigned char bidl[EPB2];      // 4 KB
    __shared__ int h4w[4][SPS];               // per-wave hist (32 subs)
    __shared__ int f4w[4][SPS];
    __shared__ int lscanx[SPS], lbase[SPS];
    unsigned rec[EPB2 / 256];
    int tid = threadIdx.x;
    int wv = tid >> 6;
    if (tid < 128) h4w[tid >> 5][tid & 31] = 0;
    __syncthreads();
#pragma unroll
    for (int k = 0; k < EPB2 / 256; ++k) {
        int i = k * 256 + tid;
        rec[k] = 0xFFFFFFFFu;
        if (i < cnt) {
            unsigned r = src[i];
            rec[k] = r;
            atomicAdd(&h4w[wv][(r >> SUB_SHIFT) & (SPS - 1)], 1);
        }
    }
    __syncthreads();
    if (tid < 32) {
        int t0 = h4w[0][tid], t1 = h4w[1][tid], t2 = h4w[2][tid], t3 = h4w[3][tid];
        int tot = t0 + t1 + t2 + t3;
        int inc = tot;
#pragma unroll
        for (int off = 1; off < 32; off <<= 1) {
            int t = __shfl_up(inc, off);
            if (tid >= off) inc += t;
        }
        int excl = inc - tot;
        lscanx[tid] = excl;
        lbase[tid] = tot ? atomicAdd(&subcur[sb * SPS + tid], tot) : 0;
        f4w[0][tid] = excl;
        f4w[1][tid] = excl + t0;
        f4w[2][tid] = excl + t0 + t1;
        f4w[3][tid] = excl + t0 + t1 + t2;
    }
    __syncthreads();
#pragma unroll
    for (int k = 0; k < EPB2 / 256; ++k) {
        if (rec[k] != 0xFFFFFFFFu) {
            int b = (rec[k] >> SUB_SHIFT) & (SPS - 1);
            int loc = atomicAdd(&f4w[wv][b], 1);
            stage[loc] = rec[k];
            bidl[loc] = (unsigned char)b;
        }
    }
    __syncthreads();
    for (int k = 0; k < EPB2 / 256; ++k) {
        int idx = k * 256 + tid;
        if (idx < cnt) {
            unsigned r = stage[idx];
            int b = bidl[idx];
            unsigned packed = ((r >> SB_SHIFT) << SUB_SHIFT) | (r & (SUB - 1));
            b2[(size_t)(sb * SPS + b) * SUBCAP + lbase[b] + (idx - lscanx[b])] = packed;
        }
    }
}

// ---------- fill3: one 256-thr block per 256-node sub + fused prescale ----------
__global__ __launch_bounds__(256) void k_fill3(const unsigned* __restrict__ b2,
                                               const int* __restrict__ subcur,
                                               const f4* __restrict__ x,
                                               float* __restrict__ dinv,
                                               i2* __restrict__ rp2,
                                               int* __restrict__ col,
                                               h4* __restrict__ g0, int N) {
    __shared__ unsigned stage[SUBCAP];        // 24 KB
    __shared__ int h[SUB];                    // 1 KB
    __shared__ float dl[SUB];                 // 1 KB
    __shared__ int wsum[4];
    int tid = threadIdx.x;
    int g = blockIdx.x;
    int count = subcur[g];
    int sbase = g * SUBCAP;
    int n0 = g << SUB_SHIFT;

    h[tid] = 0;
    for (int e = tid; e < count; e += 256) stage[e] = b2[(size_t)sbase + e];
    __syncthreads();
    for (int e = tid; e < count; e += 256) atomicAdd(&h[stage[e] & (SUB - 1)], 1);
    __syncthreads();

    int deg = h[tid];
    int lane = tid & 63, wid = tid >> 6;
    int inc = deg;
#pragma unroll
    for (int off = 1; off < 64; off <<= 1) {
        int t = __shfl_up(inc, off);
        if (lane >= off) inc += t;
    }
    if (lane == 63) wsum[wid] = inc;
    __syncthreads();
    if (wid == 0) {
        int v = (lane < 4) ? wsum[lane] : 0;
#pragma unroll
        for (int off = 1; off < 4; off <<= 1) {
            int t = __shfl_up(v, off);
            if (lane >= off) v += t;
        }
        if (lane < 4) wsum[lane] = v;
    }
    __syncthreads();
    int incl = inc + (wid ? wsum[wid - 1] : 0);
    int excl = incl - deg;

    int node = n0 + tid;
    float di = rsqrtf(1.0f + (float)deg);
    dl[tid] = di;
    if (node < N) {
        dinv[node] = di;
        rp2[node] = (i2){sbase + excl, sbase + incl};
    }
    h[tid] = excl;
    __syncthreads();

    for (int e = tid; e < count; e += 256) {
        unsigned r = stage[e];
        int slot = sbase + atomicAdd(&h[r & (SUB - 1)], 1);
        col[slot] = (int)(r >> SUB_SHIFT);
    }

    // fused prescale for this block's nodes: g0 = fp16(dinv .* x), coalesced
    for (int idx = tid; idx < SUB * 8; idx += 256) {
        int nl = idx >> 3;
        int gi = n0 * 8 + idx;
        if (n0 + nl < N) {
            f4 v = dl[nl] * x[gi];
            g0[gi] = __builtin_convertvector(v, h4);
        }
    }
}

// ---------- Mid hop (hops 1,2): R8 config ----------
__global__ __launch_bounds__(256) void k_hop_gather(const i2* __restrict__ rp2,
                                                    const int* __restrict__ col,
                                                    const float* __restrict__ dinv,
                                                    const h4* __restrict__ gin,
                                                    h4* __restrict__ gout, int N) {
    int t = blockIdx.x * blockDim.x + threadIdx.x;
    int n = t >> 3;
    if (n >= N) return;
    int q = t & 7;
    i2 r2 = rp2[n];
    int e0 = r2.x, e1 = r2.y;
    f4 a0 = __builtin_convertvector(gin[n * 8 + q], f4);  // self-loop term
    f4 a1 = {0.f, 0.f, 0.f, 0.f};
    int e = e0;
    for (; e + 3 < e1; e += 4) {
        int s0 = col[e], s1 = col[e + 1], s2 = col[e + 2], s3 = col[e + 3];
        h4 h0 = gin[s0 * 8 + q];
        h4 h1 = gin[s1 * 8 + q];
        h4 h2 = gin[s2 * 8 + q];
        h4 h3 = gin[s3 * 8 + q];
        a0 += __builtin_convertvector(h0, f4);
        a1 += __builtin_convertvector(h1, f4);
        a0 += __builtin_convertvector(h2, f4);
        a1 += __builtin_convertvector(h3, f4);
    }
    for (; e < e1; ++e) a0 += __builtin_convertvector(gin[col[e] * 8 + q], f4);
    float di = dinv[n];
    float sc = di * di;
    f4 r = sc * (a0 + a1);
    gout[n * 8 + q] = __builtin_convertvector(r, h4);
}

// ---------- Final hop FUSED with linear; conflict-free epilogue ----------
// Block = 256 thr = 32 nodes x 8 lanes (gather), then 8 passes of 4 nodes x 64 o.
__global__ __launch_bounds__(256) void k_hop3_linear(const i2* __restrict__ rp2,
                                                     const int* __restrict__ col,
                                                     const float* __restrict__ dinv,
                                                     const h4* __restrict__ gin,
                                                     const float* __restrict__ W,
                                                     const float* __restrict__ bias,
                                                     float* __restrict__ out, int N) {
    __shared__ float Wl[F_OUT][F_IN + 1];   // 8.4 KB
    __shared__ float hl[32][F_IN + 1];      // 4.2 KB
    int tid = threadIdx.x;
    for (int idx = tid; idx < F_OUT * F_IN; idx += 256)
        Wl[idx >> 5][idx & 31] = W[idx];

    int nl = tid >> 3;                 // 0..31 local node
    int q = tid & 7;
    int nbase = blockIdx.x * 32;
    int n = nbase + nl;
    if (n < N) {
        i2 r2 = rp2[n];
        int e0 = r2.x, e1 = r2.y;
        f4 a0 = __builtin_convertvector(gin[n * 8 + q], f4);
        f4 a1 = {0.f, 0.f, 0.f, 0.f};
        int e = e0;
        for (; e + 3 < e1; e += 4) {
            int s0 = col[e], s1 = col[e + 1], s2 = col[e + 2], s3 = col[e + 3];
            h4 h0 = gin[s0 * 8 + q];
            h4 h1 = gin[s1 * 8 + q];
            h4 h2 = gin[s2 * 8 + q];
            h4 h3 = gin[s3 * 8 + q];
            a0 += __builtin_convertvector(h0, f4);
            a1 += __builtin_convertvector(h1, f4);
            a0 += __builtin_convertvector(h2, f4);
            a1 += __builtin_convertvector(h3, f4);
        }
        for (; e < e1; ++e) a0 += __builtin_convertvector(gin[col[e] * 8 + q], f4);
        float di = dinv[n];
        f4 r = di * (a0 + a1);
        hl[nl][q * 4 + 0] = r.x;
        hl[nl][q * 4 + 1] = r.y;
        hl[nl][q * 4 + 2] = r.z;
        hl[nl][q * 4 + 3] = r.w;
    }
    __syncthreads();
    // W row -> registers, conflict-free: lanes o=0..63 read Wl[o][f], bank (o+f)%32
    int o = tid & 63;
    float wreg[F_IN];
#pragma unroll
    for (int f = 0; f < F_IN; ++f) wreg[f] = Wl[o][f];
    float bv = bias[o];
    // 8 passes x 4 nodes: node index wave-uniform -> hl reads broadcast
    int nchunk = tid >> 6;  // 0..3
#pragma unroll
    for (int p = 0; p < 8; ++p) {
        int nloc = p * 4 + nchunk;
        int nn = nbase + nloc;
        if (nn < N) {
            float acc = bv;
#pragma unroll
            for (int f = 0; f < F_IN; ++f) acc += hl[nloc][f] * wreg[f];
            out[(size_t)nn * F_OUT + o] = acc;
        }
    }
}

extern "C" void kernel_launch(void* const* d_in, const int* in_sizes, int n_in,
                              void* d_out, int out_size, void* d_ws, size_t ws_size,
                              hipStream_t stream) {
    const float* x  = (const float*)d_in[0];
    const int*   ei = (const int*)d_in[1];   // [2,E] int32: src row then dst row
    const float* W  = (const float*)d_in[2];
    const float* b  = (const float*)d_in[3];
    float* out = (float*)d_out;

    const int N = in_sizes[0] / F_IN;
    const int E = in_sizes[1] / 2;
    const int NSB  = (N + (1 << SB_SHIFT) - 1) >> SB_SHIFT;   // 13
    const int NSUB = (N + SUB - 1) >> SUB_SHIFT;              // 391

    // ws: scur(16) | subcur(16*32) | rp2(2N) | dinv(N) | b1 | b2 | col | hA hB hB2
    int* scur   = (int*)d_ws;
    int* subcur = scur + NSB_MAX;
    i2*  rp2    = (i2*)(subcur + NSB_MAX * SPS);
    float* dinv = (float*)(rp2 + N);
    unsigned* b1 = (unsigned*)(((uintptr_t)(dinv + N) + 255) & ~(uintptr_t)255);
    unsigned* b2 = b1 + (size_t)NSB_MAX * SCAP;
    int* col     = (int*)(b2 + (size_t)NSB_MAX * SPS * SUBCAP);
    _Float16* hA = (_Float16*)(((uintptr_t)(col + (size_t)NSB_MAX * SPS * SUBCAP) + 255)
                               & ~(uintptr_t)255);
    _Float16* hB  = hA + (size_t)N * F_IN;
    _Float16* hB2 = hB + (size_t)N * F_IN;

    const int B = 256;
    dim3 blk(B);

    hipMemsetAsync(scur, 0, (NSB_MAX + NSB_MAX * SPS) * sizeof(int), stream);

    // two-level radix partition
    k_bin1<<<dim3((E + EPB1 - 1) / EPB1), blk, 0, stream>>>(ei, scur, b1, E);
    k_bin2<<<dim3(NSB * BPS), blk, 0, stream>>>(b1, scur, subcur, b2);

    // per-sub counting sort + fused prescale (g0 -> hA)
    k_fill3<<<dim3(NSUB), blk, 0, stream>>>(b2, subcur, (const f4*)x,
                                            dinv, rp2, col, (h4*)hA, N);

    // hops 1,2: hA -> hB -> hB2
    dim3 gHop(((size_t)N * 8 + B - 1) / B);
    k_hop_gather<<<gHop, blk, 0, stream>>>(rp2, col, dinv, (const h4*)hA, (h4*)hB, N);
    k_hop_gather<<<gHop, blk, 0, stream>>>(rp2, col, dinv, (const h4*)hB, (h4*)hB2, N);

    // hop 3 fused with linear: hB2 -> out
    k_hop3_linear<<<dim3((N + 31) / 32), blk, 0, stream>>>(rp2, col, dinv,
                                                           (const h4*)hB2, W, b, out, N);
}